// Round 7
// baseline (503.570 us; speedup 1.0000x reference)
//
#include <hip/hip_runtime.h>

// ZBL pair potential + segment-sum into NUM_SYSTEMS bins.
// Inputs (setup_inputs order):
//  0: local_d_ij               float32 [16M]
//  1: radii_table              float32 [97]
//  2: local_pair_indices       int32   [2, 16M]  (row 0 = idx_i, row 1 = idx_j)
//  3: atomic_numbers           int32   [1M]
//  4: atomic_subsystem_indices int32   [1M]
// Output: float32 [10000] per-system energy.
//
// R2: LDS histograms + tree reduction (global atomics were the R1 serializer).
// R3-R6: MLP / branchless / compaction all NEUTRAL (120-131us). Invariant:
//   ~16M distinct-line touches from random gathers. 16M x 64B fills + stream
//   = ~16 B/cyc/CU == the CU vector-memory fill ceiling => L1-fill-bound,
//   94% of each gather's 64B line wasted.
// R7: flip NT hints. Gathers -> nontemporal (nt: no L1 allocation, no 64B
//   fill for 4B of data). Stream -> regular cached loads (lines fully used).

constexpr int MAXZ = 97;
constexpr int NBINS_PAD = 10240;   // 10000 bins padded for float4 flush
constexpr int DUMMY_BASE = NBINS_PAD - 64;  // per-lane trash bins (unused here)
constexpr int NREP = 512;          // histogram replicas = grid of main kernel
constexpr int NPART = 32;          // first-stage reduction fan-in groups

constexpr double LOG2E_D = 1.4426950408889634;
constexpr float A_INV = (float)(1.0 / (0.8854 * 0.0529177210903));
constexpr float C1 = (float)(-3.2    * LOG2E_D);
constexpr float C2 = (float)(-0.9423 * LOG2E_D);
constexpr float C3 = (float)(-0.4029 * LOG2E_D);
constexpr float C4 = (float)(-0.2016 * LOG2E_D);
constexpr float COUL = 138.9354576f;

typedef int   iv4 __attribute__((ext_vector_type(4)));
typedef float fv4 __attribute__((ext_vector_type(4)));
typedef float fv2 __attribute__((ext_vector_type(2)));

__global__ void zero_kernel(float* __restrict__ out, int n) {
    int i = blockIdx.x * blockDim.x + threadIdx.x;
    if (i < n) out[i] = 0.0f;
}

// packed[i] = z | (seg << 8)   (z < 97 fits in 8 bits, seg < 10000 fits in 24)
__global__ void pack_kernel(const int* __restrict__ z,
                            const int* __restrict__ seg,
                            unsigned int* __restrict__ packed, int n) {
    int i = blockIdx.x * blockDim.x + threadIdx.x;
    if (i < n)
        packed[i] = (unsigned int)z[i] | ((unsigned int)seg[i] << 8);
}

// Shared edge-energy math (tables in LDS).
__device__ __forceinline__ float zbl_energy(int zi, int zj, float d,
                                            const fv2* s_rz, bool& pass) {
    fv2 rzi = s_rz[zi];
    fv2 rzj = s_rz[zj];
    float rsum = rzi.x + rzj.x;
    pass = (d < rsum);
    float dA = d * (rzi.y + rzj.y) * A_INV;
    float f = 0.1818f  * __builtin_exp2f(C1 * dA)
            + 0.5099f  * __builtin_exp2f(C2 * dA)
            + 0.2802f  * __builtin_exp2f(C3 * dA)
            + 0.02817f * __builtin_exp2f(C4 * dA);
    float tt = d * __builtin_amdgcn_rcpf(rsum);          // in [0,1)
    // cos(pi*t) = v_cos(t/2)  (v_cos input is in revolutions)
    float phi = 0.5f * (__builtin_amdgcn_cosf(0.5f * tt) + 1.0f);
    return f * phi * (COUL * (float)zi * (float)zj) * __builtin_amdgcn_rcpf(d);
}

// ---------------- main path: LDS histogram, no global atomics ---------------

__global__ __launch_bounds__(1024)
void zbl_hist_kernel(const float* __restrict__ d_ij,
                     const float* __restrict__ radii,
                     const int* __restrict__ idx_i,
                     const int* __restrict__ idx_j,
                     const unsigned int* __restrict__ packed,
                     float* __restrict__ rep,     // [NREP][NBINS_PAD]
                     int n_edges) {
    __shared__ float s_hist[NBINS_PAD];  // 40 KiB
    __shared__ fv2 s_rz[128];            // {radius, z^0.23} -> ds_read_b64
    const int t = threadIdx.x;

    for (int b = t; b < NBINS_PAD; b += 1024) s_hist[b] = 0.0f;
    if (t < 128) {
        fv2 v;
        v.x = (t < MAXZ) ? radii[t] : 0.0f;
        v.y = __builtin_exp2f(0.23f * __builtin_log2f((float)t));  // z^0.23
        s_rz[t] = v;
    }
    __syncthreads();

    const int ngrp = n_edges >> 3;   // groups of 8 edges
    const int stride = gridDim.x * blockDim.x;
    for (int g = blockIdx.x * blockDim.x + t; g < ngrp; g += stride) {
        // Stream loads: REGULAR cached (every byte of the line is consumed).
        const iv4* pii = reinterpret_cast<const iv4*>(idx_i) + 2 * g;
        const iv4* pjj = reinterpret_cast<const iv4*>(idx_j) + 2 * g;
        const fv4* pdd = reinterpret_cast<const fv4*>(d_ij) + 2 * g;
        iv4 ii0 = pii[0];
        iv4 ii1 = pii[1];
        iv4 jj0 = pjj[0];
        iv4 jj1 = pjj[1];
        fv4 dd0 = pdd[0];
        fv4 dd1 = pdd[1];

        int ia[8], ja[8];
        float da[8];
#pragma unroll
        for (int k = 0; k < 4; ++k) {
            ia[k] = ii0[k]; ia[4 + k] = ii1[k];
            ja[k] = jj0[k]; ja[4 + k] = jj1[k];
            da[k] = dd0[k]; da[4 + k] = dd1[k];
        }

        // Gathers: NON-TEMPORAL (nt => no L1 line allocation; avoid pulling a
        // 64B fill to deliver 4B). All 16 issued back-to-back; dead lanes
        // (i>=j) read packed[0] — one always-hot line.
        unsigned int pia[8], pja[8];
#pragma unroll
        for (int k = 0; k < 8; ++k) {
            bool m = ia[k] < ja[k];
            pia[k] = __builtin_nontemporal_load(packed + (m ? ia[k] : 0));
            pja[k] = __builtin_nontemporal_load(packed + (m ? ja[k] : 0));
        }

        // Compute + LDS accumulate (branch-guarded, R3-style).
#pragma unroll
        for (int k = 0; k < 8; ++k) {
            if (ia[k] < ja[k]) {
                int zi = (int)(pia[k] & 0xFFu);
                int zj = (int)(pja[k] & 0xFFu);
                int seg = (int)(pia[k] >> 8);
                bool pass;
                float e = zbl_energy(zi, zj, da[k], s_rz, pass);
                if (pass) atomicAdd(&s_hist[seg], e);
            }
        }
    }

    // Tail (n_edges % 8 != 0): at most 7 edges, one thread handles them.
    if (blockIdx.x == 0 && t == 0) {
        for (int e = ngrp << 3; e < n_edges; ++e) {
            int i = idx_i[e], j = idx_j[e];
            if (i < j) {
                unsigned int pi = packed[i], pj = packed[j];
                bool pass;
                float en = zbl_energy((int)(pi & 0xFFu), (int)(pj & 0xFFu),
                                      d_ij[e], s_rz, pass);
                if (pass) atomicAdd(&s_hist[(int)(pi >> 8)], en);
            }
        }
    }

    __syncthreads();
    // Flush histogram to this block's replica row (coalesced float4 stores).
    fv4* __restrict__ rp =
        reinterpret_cast<fv4*>(rep + (size_t)blockIdx.x * NBINS_PAD);
    const fv4* sh = reinterpret_cast<const fv4*>(s_hist);
    for (int q = t; q < NBINS_PAD / 4; q += 1024)
        rp[q] = sh[q];
}

// Stage 1: partial[s][bin] = sum over replica rows r = s, s+NPART, ...
__global__ __launch_bounds__(256)
void reduce1_kernel(const float* __restrict__ rep,
                    float* __restrict__ partial) {
    int bin = blockIdx.x * 256 + threadIdx.x;
    int s = blockIdx.y;
    float acc = 0.0f;
    for (int r = s; r < NREP; r += NPART)
        acc += rep[(size_t)r * NBINS_PAD + bin];
    partial[(size_t)s * NBINS_PAD + bin] = acc;
}

// Stage 2: out[bin] = sum over NPART partials.
__global__ __launch_bounds__(256)
void reduce2_kernel(const float* __restrict__ partial,
                    float* __restrict__ out, int out_size) {
    int bin = blockIdx.x * 256 + threadIdx.x;
    if (bin < out_size) {
        float acc = 0.0f;
        for (int s = 0; s < NPART; ++s)
            acc += partial[(size_t)s * NBINS_PAD + bin];
        out[bin] = acc;
    }
}

// ---------------- fallback path (R1): direct global atomics ----------------

template <bool PACKED>
__global__ __launch_bounds__(256)
void zbl_atomic_kernel(const float* __restrict__ d_ij,
                       const float* __restrict__ radii,
                       const int* __restrict__ idx_i,
                       const int* __restrict__ idx_j,
                       const unsigned int* __restrict__ packed,
                       const int* __restrict__ atomz,
                       const int* __restrict__ subsys,
                       float* __restrict__ out,
                       int nchunk) {
    __shared__ fv2 s_rz[128];
    int t = threadIdx.x;
    if (t < 128) {
        fv2 v;
        v.x = (t < MAXZ) ? radii[t] : 0.0f;
        v.y = __builtin_exp2f(0.23f * __builtin_log2f((float)t));
        s_rz[t] = v;
    }
    __syncthreads();

    int chunk = blockIdx.x * blockDim.x + threadIdx.x;
    if (chunk >= nchunk) return;

    iv4 ii = reinterpret_cast<const iv4*>(idx_i)[chunk];
    iv4 jj = reinterpret_cast<const iv4*>(idx_j)[chunk];
    fv4 dd = reinterpret_cast<const fv4*>(d_ij)[chunk];

#pragma unroll
    for (int k = 0; k < 4; ++k) {
        int i = ii[k];
        int j = jj[k];
        float d = dd[k];
        if (i < j) {
            int zi, zj, seg;
            if (PACKED) {
                unsigned int pi = packed[i];
                unsigned int pj = packed[j];
                zi = (int)(pi & 0xFFu);
                zj = (int)(pj & 0xFFu);
                seg = (int)(pi >> 8);
            } else {
                zi = atomz[i];
                zj = atomz[j];
                seg = subsys[i];
            }
            bool pass;
            float e = zbl_energy(zi, zj, d, s_rz, pass);
            if (pass) atomicAdd(out + seg, e);
        }
    }
}

extern "C" void kernel_launch(void* const* d_in, const int* in_sizes, int n_in,
                              void* d_out, int out_size, void* d_ws, size_t ws_size,
                              hipStream_t stream) {
    const float* d_ij  = (const float*)d_in[0];
    const float* radii = (const float*)d_in[1];
    const int* pairs   = (const int*)d_in[2];
    const int* atomz   = (const int*)d_in[3];
    const int* subsys  = (const int*)d_in[4];
    float* out = (float*)d_out;

    const int n_edges = in_sizes[2] / 2;   // 16,000,000
    const int n_atoms = in_sizes[3];       // 1,000,000
    const int* idx_i = pairs;
    const int* idx_j = pairs + n_edges;

    const size_t packed_bytes = (size_t)n_atoms * sizeof(unsigned int);
    const size_t rep_bytes = (size_t)NREP * NBINS_PAD * sizeof(float);
    const size_t part_bytes = (size_t)NPART * NBINS_PAD * sizeof(float);

    if (ws_size >= packed_bytes + rep_bytes + part_bytes) {
        unsigned int* packed = (unsigned int*)d_ws;
        float* rep = (float*)((char*)d_ws + packed_bytes);
        float* partial = (float*)((char*)d_ws + packed_bytes + rep_bytes);

        pack_kernel<<<(n_atoms + 255) / 256, 256, 0, stream>>>(atomz, subsys,
                                                               packed, n_atoms);
        zbl_hist_kernel<<<NREP, 1024, 0, stream>>>(
            d_ij, radii, idx_i, idx_j, packed, rep, n_edges);
        dim3 g1(NBINS_PAD / 256, NPART);
        reduce1_kernel<<<g1, 256, 0, stream>>>(rep, partial);
        reduce2_kernel<<<(out_size + 255) / 256, 256, 0, stream>>>(
            partial, out, out_size);
    } else {
        // Fallback: direct-atomic path (R1)
        zero_kernel<<<(out_size + 255) / 256, 256, 0, stream>>>(out, out_size);
        const int nchunk = n_edges / 4;
        const int blocks = (nchunk + 255) / 256;
        if (ws_size >= packed_bytes) {
            unsigned int* packed = (unsigned int*)d_ws;
            pack_kernel<<<(n_atoms + 255) / 256, 256, 0, stream>>>(
                atomz, subsys, packed, n_atoms);
            zbl_atomic_kernel<true><<<blocks, 256, 0, stream>>>(
                d_ij, radii, idx_i, idx_j, packed, atomz, subsys, out, nchunk);
        } else {
            zbl_atomic_kernel<false><<<blocks, 256, 0, stream>>>(
                d_ij, radii, idx_i, idx_j, nullptr, atomz, subsys, out, nchunk);
        }
    }
}

// Round 8
// 315.171 us; speedup vs baseline: 1.5978x; 1.5978x over previous
//
#include <hip/hip_runtime.h>

// ZBL pair potential + segment-sum into NUM_SYSTEMS bins.
// Inputs (setup_inputs order):
//  0: local_d_ij               float32 [16M]
//  1: radii_table              float32 [97]
//  2: local_pair_indices       int32   [2, 16M]  (row 0 = idx_i, row 1 = idx_j)
//  3: atomic_numbers           int32   [1M]
//  4: atomic_subsystem_indices int32   [1M]
// Output: float32 [10000] per-system energy.
//
// R2: LDS histograms + tree reduction (global atomics were the R1 serializer).
// R3-R6: MLP / branchless / compaction all NEUTRAL (120-131us).
// R7: nt-gathers bypassed L2 (FETCH 142->817MB, 333us) — latency probe:
//   confirms T = lines/CU x latency / ~64 tags model (118us pred @ L2 lat,
//   346us pred @ L3/HBM lat; measured 120-131 / 333).
// R8: agent-scope gathers (__hip_atomic_load RELAXED/AGENT): L1-bypass but
//   L2-cached. No L1 line allocation -> should not consume L1 miss tags ->
//   concurrency bound moves to per-wave vmcnt queue (63 x 24 waves/CU).

constexpr int MAXZ = 97;
constexpr int NBINS_PAD = 10240;   // 10000 bins padded for float4 flush
constexpr int NREP = 512;          // histogram replicas = grid of main kernel
constexpr int NPART = 32;          // first-stage reduction fan-in groups

constexpr double LOG2E_D = 1.4426950408889634;
constexpr float A_INV = (float)(1.0 / (0.8854 * 0.0529177210903));
constexpr float C1 = (float)(-3.2    * LOG2E_D);
constexpr float C2 = (float)(-0.9423 * LOG2E_D);
constexpr float C3 = (float)(-0.4029 * LOG2E_D);
constexpr float C4 = (float)(-0.2016 * LOG2E_D);
constexpr float COUL = 138.9354576f;

typedef int   iv4 __attribute__((ext_vector_type(4)));
typedef float fv4 __attribute__((ext_vector_type(4)));
typedef float fv2 __attribute__((ext_vector_type(2)));

__global__ void zero_kernel(float* __restrict__ out, int n) {
    int i = blockIdx.x * blockDim.x + threadIdx.x;
    if (i < n) out[i] = 0.0f;
}

// packed[i] = z | (seg << 8)   (z < 97 fits in 8 bits, seg < 10000 fits in 24)
__global__ void pack_kernel(const int* __restrict__ z,
                            const int* __restrict__ seg,
                            unsigned int* __restrict__ packed, int n) {
    int i = blockIdx.x * blockDim.x + threadIdx.x;
    if (i < n)
        packed[i] = (unsigned int)z[i] | ((unsigned int)seg[i] << 8);
}

// Shared edge-energy math (tables in LDS).
__device__ __forceinline__ float zbl_energy(int zi, int zj, float d,
                                            const fv2* s_rz, bool& pass) {
    fv2 rzi = s_rz[zi];
    fv2 rzj = s_rz[zj];
    float rsum = rzi.x + rzj.x;
    pass = (d < rsum);
    float dA = d * (rzi.y + rzj.y) * A_INV;
    float f = 0.1818f  * __builtin_exp2f(C1 * dA)
            + 0.5099f  * __builtin_exp2f(C2 * dA)
            + 0.2802f  * __builtin_exp2f(C3 * dA)
            + 0.02817f * __builtin_exp2f(C4 * dA);
    float tt = d * __builtin_amdgcn_rcpf(rsum);          // in [0,1)
    // cos(pi*t) = v_cos(t/2)  (v_cos input is in revolutions)
    float phi = 0.5f * (__builtin_amdgcn_cosf(0.5f * tt) + 1.0f);
    return f * phi * (COUL * (float)zi * (float)zj) * __builtin_amdgcn_rcpf(d);
}

__device__ __forceinline__ unsigned int gather_agent(const unsigned int* p) {
    // Agent-scope relaxed load: global_load_dword with coherent policy —
    // bypasses L1 (no line allocation / no 64B fill), caches in L2.
    return __hip_atomic_load(p, __ATOMIC_RELAXED, __HIP_MEMORY_SCOPE_AGENT);
}

// ---------------- main path: LDS histogram, no global atomics ---------------

__global__ __launch_bounds__(1024)
void zbl_hist_kernel(const float* __restrict__ d_ij,
                     const float* __restrict__ radii,
                     const int* __restrict__ idx_i,
                     const int* __restrict__ idx_j,
                     const unsigned int* __restrict__ packed,
                     float* __restrict__ rep,     // [NREP][NBINS_PAD]
                     int n_edges) {
    __shared__ float s_hist[NBINS_PAD];  // 40 KiB
    __shared__ fv2 s_rz[128];            // {radius, z^0.23} -> ds_read_b64
    const int t = threadIdx.x;

    for (int b = t; b < NBINS_PAD; b += 1024) s_hist[b] = 0.0f;
    if (t < 128) {
        fv2 v;
        v.x = (t < MAXZ) ? radii[t] : 0.0f;
        v.y = __builtin_exp2f(0.23f * __builtin_log2f((float)t));  // z^0.23
        s_rz[t] = v;
    }
    __syncthreads();

    const int ngrp = n_edges >> 3;   // groups of 8 edges
    const int stride = gridDim.x * blockDim.x;
    for (int g = blockIdx.x * blockDim.x + t; g < ngrp; g += stride) {
        const iv4* pii = reinterpret_cast<const iv4*>(idx_i) + 2 * g;
        const iv4* pjj = reinterpret_cast<const iv4*>(idx_j) + 2 * g;
        const fv4* pdd = reinterpret_cast<const fv4*>(d_ij) + 2 * g;
        // Non-temporal stream loads (as R4): lines are fully consumed once.
        iv4 ii0 = __builtin_nontemporal_load(pii);
        iv4 ii1 = __builtin_nontemporal_load(pii + 1);
        iv4 jj0 = __builtin_nontemporal_load(pjj);
        iv4 jj1 = __builtin_nontemporal_load(pjj + 1);
        fv4 dd0 = __builtin_nontemporal_load(pdd);
        fv4 dd1 = __builtin_nontemporal_load(pdd + 1);

        int ia[8], ja[8];
        float da[8];
#pragma unroll
        for (int k = 0; k < 4; ++k) {
            ia[k] = ii0[k]; ia[4 + k] = ii1[k];
            ja[k] = jj0[k]; ja[4 + k] = jj1[k];
            da[k] = dd0[k]; da[4 + k] = dd1[k];
        }

        // All 16 gathers issued back-to-back, agent scope (L1-bypass,
        // L2-cached). Dead lanes (i>=j) read packed[0] — one hot line.
        unsigned int pia[8], pja[8];
#pragma unroll
        for (int k = 0; k < 8; ++k) {
            bool m = ia[k] < ja[k];
            pia[k] = gather_agent(packed + (m ? ia[k] : 0));
            pja[k] = gather_agent(packed + (m ? ja[k] : 0));
        }

        // Compute + LDS accumulate (branch-guarded, as R4).
#pragma unroll
        for (int k = 0; k < 8; ++k) {
            if (ia[k] < ja[k]) {
                int zi = (int)(pia[k] & 0xFFu);
                int zj = (int)(pja[k] & 0xFFu);
                int seg = (int)(pia[k] >> 8);
                bool pass;
                float e = zbl_energy(zi, zj, da[k], s_rz, pass);
                if (pass) atomicAdd(&s_hist[seg], e);
            }
        }
    }

    // Tail (n_edges % 8 != 0): at most 7 edges, one thread handles them.
    if (blockIdx.x == 0 && t == 0) {
        for (int e = ngrp << 3; e < n_edges; ++e) {
            int i = idx_i[e], j = idx_j[e];
            if (i < j) {
                unsigned int pi = packed[i], pj = packed[j];
                bool pass;
                float en = zbl_energy((int)(pi & 0xFFu), (int)(pj & 0xFFu),
                                      d_ij[e], s_rz, pass);
                if (pass) atomicAdd(&s_hist[(int)(pi >> 8)], en);
            }
        }
    }

    __syncthreads();
    // Flush histogram to this block's replica row (coalesced float4 stores).
    fv4* __restrict__ rp =
        reinterpret_cast<fv4*>(rep + (size_t)blockIdx.x * NBINS_PAD);
    const fv4* sh = reinterpret_cast<const fv4*>(s_hist);
    for (int q = t; q < NBINS_PAD / 4; q += 1024)
        rp[q] = sh[q];
}

// Stage 1: partial[s][bin] = sum over replica rows r = s, s+NPART, ...
__global__ __launch_bounds__(256)
void reduce1_kernel(const float* __restrict__ rep,
                    float* __restrict__ partial) {
    int bin = blockIdx.x * 256 + threadIdx.x;
    int s = blockIdx.y;
    float acc = 0.0f;
    for (int r = s; r < NREP; r += NPART)
        acc += rep[(size_t)r * NBINS_PAD + bin];
    partial[(size_t)s * NBINS_PAD + bin] = acc;
}

// Stage 2: out[bin] = sum over NPART partials.
__global__ __launch_bounds__(256)
void reduce2_kernel(const float* __restrict__ partial,
                    float* __restrict__ out, int out_size) {
    int bin = blockIdx.x * 256 + threadIdx.x;
    if (bin < out_size) {
        float acc = 0.0f;
        for (int s = 0; s < NPART; ++s)
            acc += partial[(size_t)s * NBINS_PAD + bin];
        out[bin] = acc;
    }
}

// ---------------- fallback path (R1): direct global atomics ----------------

template <bool PACKED>
__global__ __launch_bounds__(256)
void zbl_atomic_kernel(const float* __restrict__ d_ij,
                       const float* __restrict__ radii,
                       const int* __restrict__ idx_i,
                       const int* __restrict__ idx_j,
                       const unsigned int* __restrict__ packed,
                       const int* __restrict__ atomz,
                       const int* __restrict__ subsys,
                       float* __restrict__ out,
                       int nchunk) {
    __shared__ fv2 s_rz[128];
    int t = threadIdx.x;
    if (t < 128) {
        fv2 v;
        v.x = (t < MAXZ) ? radii[t] : 0.0f;
        v.y = __builtin_exp2f(0.23f * __builtin_log2f((float)t));
        s_rz[t] = v;
    }
    __syncthreads();

    int chunk = blockIdx.x * blockDim.x + threadIdx.x;
    if (chunk >= nchunk) return;

    iv4 ii = reinterpret_cast<const iv4*>(idx_i)[chunk];
    iv4 jj = reinterpret_cast<const iv4*>(idx_j)[chunk];
    fv4 dd = reinterpret_cast<const fv4*>(d_ij)[chunk];

#pragma unroll
    for (int k = 0; k < 4; ++k) {
        int i = ii[k];
        int j = jj[k];
        float d = dd[k];
        if (i < j) {
            int zi, zj, seg;
            if (PACKED) {
                unsigned int pi = packed[i];
                unsigned int pj = packed[j];
                zi = (int)(pi & 0xFFu);
                zj = (int)(pj & 0xFFu);
                seg = (int)(pi >> 8);
            } else {
                zi = atomz[i];
                zj = atomz[j];
                seg = subsys[i];
            }
            bool pass;
            float e = zbl_energy(zi, zj, d, s_rz, pass);
            if (pass) atomicAdd(out + seg, e);
        }
    }
}

extern "C" void kernel_launch(void* const* d_in, const int* in_sizes, int n_in,
                              void* d_out, int out_size, void* d_ws, size_t ws_size,
                              hipStream_t stream) {
    const float* d_ij  = (const float*)d_in[0];
    const float* radii = (const float*)d_in[1];
    const int* pairs   = (const int*)d_in[2];
    const int* atomz   = (const int*)d_in[3];
    const int* subsys  = (const int*)d_in[4];
    float* out = (float*)d_out;

    const int n_edges = in_sizes[2] / 2;   // 16,000,000
    const int n_atoms = in_sizes[3];       // 1,000,000
    const int* idx_i = pairs;
    const int* idx_j = pairs + n_edges;

    const size_t packed_bytes = (size_t)n_atoms * sizeof(unsigned int);
    const size_t rep_bytes = (size_t)NREP * NBINS_PAD * sizeof(float);
    const size_t part_bytes = (size_t)NPART * NBINS_PAD * sizeof(float);

    if (ws_size >= packed_bytes + rep_bytes + part_bytes) {
        unsigned int* packed = (unsigned int*)d_ws;
        float* rep = (float*)((char*)d_ws + packed_bytes);
        float* partial = (float*)((char*)d_ws + packed_bytes + rep_bytes);

        pack_kernel<<<(n_atoms + 255) / 256, 256, 0, stream>>>(atomz, subsys,
                                                               packed, n_atoms);
        zbl_hist_kernel<<<NREP, 1024, 0, stream>>>(
            d_ij, radii, idx_i, idx_j, packed, rep, n_edges);
        dim3 g1(NBINS_PAD / 256, NPART);
        reduce1_kernel<<<g1, 256, 0, stream>>>(rep, partial);
        reduce2_kernel<<<(out_size + 255) / 256, 256, 0, stream>>>(
            partial, out, out_size);
    } else {
        // Fallback: direct-atomic path (R1)
        zero_kernel<<<(out_size + 255) / 256, 256, 0, stream>>>(out, out_size);
        const int nchunk = n_edges / 4;
        const int blocks = (nchunk + 255) / 256;
        if (ws_size >= packed_bytes) {
            unsigned int* packed = (unsigned int*)d_ws;
            pack_kernel<<<(n_atoms + 255) / 256, 256, 0, stream>>>(
                atomz, subsys, packed, n_atoms);
            zbl_atomic_kernel<true><<<blocks, 256, 0, stream>>>(
                d_ij, radii, idx_i, idx_j, packed, atomz, subsys, out, nchunk);
        } else {
            zbl_atomic_kernel<false><<<blocks, 256, 0, stream>>>(
                d_ij, radii, idx_i, idx_j, nullptr, atomz, subsys, out, nchunk);
        }
    }
}

// Round 9
// 305.666 us; speedup vs baseline: 1.6475x; 1.0311x over previous
//
#include <hip/hip_runtime.h>

// ZBL pair potential + segment-sum into NUM_SYSTEMS bins.
// Inputs (setup_inputs order):
//  0: local_d_ij               float32 [16M]
//  1: radii_table              float32 [97]
//  2: local_pair_indices       int32   [2, 16M]  (row 0 = idx_i, row 1 = idx_j)
//  3: atomic_numbers           int32   [1M]
//  4: atomic_subsystem_indices int32   [1M]
// Output: float32 [10000] per-system energy.
//
// R2:  LDS histograms + tree reduction (global atomics were the R1 serializer).
// R3-R8: MLP / branchless / compaction / agent-scope ALL NEUTRAL (120-131us);
//   nt (L2-bypass) = 333us. Model: ~16M distinct random line-requests served
//   at ~64 in-flight misses/CU x ~270cyc L2 latency => ~125us floor,
//   policy/scope/MLP independent. Only lever: request count.
// R9: physics-gated j-gather elision. phi=0 when d >= r_i + r_j and
//   r_j <= RMAX => edges with d >= r_i + RMAX provably contribute 0 without
//   fetching j (~19% of j-gathers elided; masked lanes -> packed[0], free).

constexpr int MAXZ = 97;
constexpr int NBINS_PAD = 10240;   // 10000 bins padded for float4 flush
constexpr int NREP = 512;          // histogram replicas = grid of main kernel
constexpr int NPART = 32;          // first-stage reduction fan-in groups

constexpr double LOG2E_D = 1.4426950408889634;
constexpr float A_INV = (float)(1.0 / (0.8854 * 0.0529177210903));
constexpr float C1 = (float)(-3.2    * LOG2E_D);
constexpr float C2 = (float)(-0.9423 * LOG2E_D);
constexpr float C3 = (float)(-0.4029 * LOG2E_D);
constexpr float C4 = (float)(-0.2016 * LOG2E_D);
constexpr float COUL = 138.9354576f;
constexpr float RMAX = 0.26f;      // max radius in table (Z=87); r_j <= RMAX

typedef int   iv4 __attribute__((ext_vector_type(4)));
typedef float fv4 __attribute__((ext_vector_type(4)));
typedef float fv2 __attribute__((ext_vector_type(2)));

__global__ void zero_kernel(float* __restrict__ out, int n) {
    int i = blockIdx.x * blockDim.x + threadIdx.x;
    if (i < n) out[i] = 0.0f;
}

// packed[i] = z | (seg << 8)   (z < 97 fits in 8 bits, seg < 10000 fits in 24)
__global__ void pack_kernel(const int* __restrict__ z,
                            const int* __restrict__ seg,
                            unsigned int* __restrict__ packed, int n) {
    int i = blockIdx.x * blockDim.x + threadIdx.x;
    if (i < n)
        packed[i] = (unsigned int)z[i] | ((unsigned int)seg[i] << 8);
}

// Edge-energy math given both z's (tables in LDS). pass=false => contributes 0.
__device__ __forceinline__ float zbl_energy(int zi, int zj, float d,
                                            const fv2* s_rz, bool& pass) {
    fv2 rzi = s_rz[zi];
    fv2 rzj = s_rz[zj];
    float rsum = rzi.x + rzj.x;
    pass = (d < rsum);
    float dA = d * (rzi.y + rzj.y) * A_INV;
    float f = 0.1818f  * __builtin_exp2f(C1 * dA)
            + 0.5099f  * __builtin_exp2f(C2 * dA)
            + 0.2802f  * __builtin_exp2f(C3 * dA)
            + 0.02817f * __builtin_exp2f(C4 * dA);
    float tt = d * __builtin_amdgcn_rcpf(rsum);          // in [0,1)
    // cos(pi*t) = v_cos(t/2)  (v_cos input is in revolutions)
    float phi = 0.5f * (__builtin_amdgcn_cosf(0.5f * tt) + 1.0f);
    return f * phi * (COUL * (float)zi * (float)zj) * __builtin_amdgcn_rcpf(d);
}

// ---------------- main path: LDS histogram, no global atomics ---------------

__global__ __launch_bounds__(1024)
void zbl_hist_kernel(const float* __restrict__ d_ij,
                     const float* __restrict__ radii,
                     const int* __restrict__ idx_i,
                     const int* __restrict__ idx_j,
                     const unsigned int* __restrict__ packed,
                     float* __restrict__ rep,     // [NREP][NBINS_PAD]
                     int n_edges) {
    __shared__ float s_hist[NBINS_PAD];  // 40 KiB
    __shared__ fv2 s_rz[128];            // {radius, z^0.23} -> ds_read_b64
    const int t = threadIdx.x;

    for (int b = t; b < NBINS_PAD; b += 1024) s_hist[b] = 0.0f;
    if (t < 128) {
        fv2 v;
        v.x = (t < MAXZ) ? radii[t] : 0.0f;
        v.y = __builtin_exp2f(0.23f * __builtin_log2f((float)t));  // z^0.23
        s_rz[t] = v;
    }
    __syncthreads();

    const int ngrp = n_edges >> 3;   // groups of 8 edges
    const int stride = gridDim.x * blockDim.x;
    for (int g = blockIdx.x * blockDim.x + t; g < ngrp; g += stride) {
        const iv4* pii = reinterpret_cast<const iv4*>(idx_i) + 2 * g;
        const iv4* pjj = reinterpret_cast<const iv4*>(idx_j) + 2 * g;
        const fv4* pdd = reinterpret_cast<const fv4*>(d_ij) + 2 * g;
        // Non-temporal stream loads: lines fully consumed once.
        iv4 ii0 = __builtin_nontemporal_load(pii);
        iv4 ii1 = __builtin_nontemporal_load(pii + 1);
        iv4 jj0 = __builtin_nontemporal_load(pjj);
        iv4 jj1 = __builtin_nontemporal_load(pjj + 1);
        fv4 dd0 = __builtin_nontemporal_load(pdd);
        fv4 dd1 = __builtin_nontemporal_load(pdd + 1);

        int ia[8], ja[8];
        float da[8];
#pragma unroll
        for (int k = 0; k < 4; ++k) {
            ia[k] = ii0[k]; ia[4 + k] = ii1[k];
            ja[k] = jj0[k]; ja[4 + k] = jj1[k];
            da[k] = dd0[k]; da[4 + k] = dd1[k];
        }

        // Phase 1: all 8 i-gathers back-to-back. Dead lanes (i>=j) read
        // packed[0] — one always-hot line (coalesced, free).
        unsigned int pia[8];
        bool m[8];
#pragma unroll
        for (int k = 0; k < 8; ++k) {
            m[k] = ia[k] < ja[k];
            pia[k] = packed[m[k] ? ia[k] : 0];
        }

        // Phase 2: physics gate — r_j <= RMAX, so d >= r_i + RMAX implies
        // phi = 0 regardless of j. Elide those j-gathers (mask to packed[0]).
        bool need[8];
        float ri[8];
        unsigned int pja[8];
#pragma unroll
        for (int k = 0; k < 8; ++k) {
            int zi = (int)(pia[k] & 0xFFu);
            ri[k] = s_rz[zi].x;
            need[k] = m[k] && (da[k] < ri[k] + RMAX);
            pja[k] = packed[need[k] ? ja[k] : 0];
        }

        // Phase 3: compute + LDS accumulate for surviving edges.
#pragma unroll
        for (int k = 0; k < 8; ++k) {
            if (need[k]) {
                int zi = (int)(pia[k] & 0xFFu);
                int zj = (int)(pja[k] & 0xFFu);
                int seg = (int)(pia[k] >> 8);
                bool pass;
                float e = zbl_energy(zi, zj, da[k], s_rz, pass);
                if (pass) atomicAdd(&s_hist[seg], e);
            }
        }
    }

    // Tail (n_edges % 8 != 0): at most 7 edges, one thread handles them.
    if (blockIdx.x == 0 && t == 0) {
        for (int e = ngrp << 3; e < n_edges; ++e) {
            int i = idx_i[e], j = idx_j[e];
            if (i < j) {
                unsigned int pi = packed[i], pj = packed[j];
                bool pass;
                float en = zbl_energy((int)(pi & 0xFFu), (int)(pj & 0xFFu),
                                      d_ij[e], s_rz, pass);
                if (pass) atomicAdd(&s_hist[(int)(pi >> 8)], en);
            }
        }
    }

    __syncthreads();
    // Flush histogram to this block's replica row (coalesced float4 stores).
    fv4* __restrict__ rp =
        reinterpret_cast<fv4*>(rep + (size_t)blockIdx.x * NBINS_PAD);
    const fv4* sh = reinterpret_cast<const fv4*>(s_hist);
    for (int q = t; q < NBINS_PAD / 4; q += 1024)
        rp[q] = sh[q];
}

// Stage 1: partial[s][bin] = sum over replica rows r = s, s+NPART, ...
__global__ __launch_bounds__(256)
void reduce1_kernel(const float* __restrict__ rep,
                    float* __restrict__ partial) {
    int bin = blockIdx.x * 256 + threadIdx.x;
    int s = blockIdx.y;
    float acc = 0.0f;
    for (int r = s; r < NREP; r += NPART)
        acc += rep[(size_t)r * NBINS_PAD + bin];
    partial[(size_t)s * NBINS_PAD + bin] = acc;
}

// Stage 2: out[bin] = sum over NPART partials.
__global__ __launch_bounds__(256)
void reduce2_kernel(const float* __restrict__ partial,
                    float* __restrict__ out, int out_size) {
    int bin = blockIdx.x * 256 + threadIdx.x;
    if (bin < out_size) {
        float acc = 0.0f;
        for (int s = 0; s < NPART; ++s)
            acc += partial[(size_t)s * NBINS_PAD + bin];
        out[bin] = acc;
    }
}

// ---------------- fallback path (R1): direct global atomics ----------------

template <bool PACKED>
__global__ __launch_bounds__(256)
void zbl_atomic_kernel(const float* __restrict__ d_ij,
                       const float* __restrict__ radii,
                       const int* __restrict__ idx_i,
                       const int* __restrict__ idx_j,
                       const unsigned int* __restrict__ packed,
                       const int* __restrict__ atomz,
                       const int* __restrict__ subsys,
                       float* __restrict__ out,
                       int nchunk) {
    __shared__ fv2 s_rz[128];
    int t = threadIdx.x;
    if (t < 128) {
        fv2 v;
        v.x = (t < MAXZ) ? radii[t] : 0.0f;
        v.y = __builtin_exp2f(0.23f * __builtin_log2f((float)t));
        s_rz[t] = v;
    }
    __syncthreads();

    int chunk = blockIdx.x * blockDim.x + threadIdx.x;
    if (chunk >= nchunk) return;

    iv4 ii = reinterpret_cast<const iv4*>(idx_i)[chunk];
    iv4 jj = reinterpret_cast<const iv4*>(idx_j)[chunk];
    fv4 dd = reinterpret_cast<const fv4*>(d_ij)[chunk];

#pragma unroll
    for (int k = 0; k < 4; ++k) {
        int i = ii[k];
        int j = jj[k];
        float d = dd[k];
        if (i < j) {
            int zi, zj, seg;
            if (PACKED) {
                unsigned int pi = packed[i];
                unsigned int pj = packed[j];
                zi = (int)(pi & 0xFFu);
                zj = (int)(pj & 0xFFu);
                seg = (int)(pi >> 8);
            } else {
                zi = atomz[i];
                zj = atomz[j];
                seg = subsys[i];
            }
            bool pass;
            float e = zbl_energy(zi, zj, d, s_rz, pass);
            if (pass) atomicAdd(out + seg, e);
        }
    }
}

extern "C" void kernel_launch(void* const* d_in, const int* in_sizes, int n_in,
                              void* d_out, int out_size, void* d_ws, size_t ws_size,
                              hipStream_t stream) {
    const float* d_ij  = (const float*)d_in[0];
    const float* radii = (const float*)d_in[1];
    const int* pairs   = (const int*)d_in[2];
    const int* atomz   = (const int*)d_in[3];
    const int* subsys  = (const int*)d_in[4];
    float* out = (float*)d_out;

    const int n_edges = in_sizes[2] / 2;   // 16,000,000
    const int n_atoms = in_sizes[3];       // 1,000,000
    const int* idx_i = pairs;
    const int* idx_j = pairs + n_edges;

    const size_t packed_bytes = (size_t)n_atoms * sizeof(unsigned int);
    const size_t rep_bytes = (size_t)NREP * NBINS_PAD * sizeof(float);
    const size_t part_bytes = (size_t)NPART * NBINS_PAD * sizeof(float);

    if (ws_size >= packed_bytes + rep_bytes + part_bytes) {
        unsigned int* packed = (unsigned int*)d_ws;
        float* rep = (float*)((char*)d_ws + packed_bytes);
        float* partial = (float*)((char*)d_ws + packed_bytes + rep_bytes);

        pack_kernel<<<(n_atoms + 255) / 256, 256, 0, stream>>>(atomz, subsys,
                                                               packed, n_atoms);
        zbl_hist_kernel<<<NREP, 1024, 0, stream>>>(
            d_ij, radii, idx_i, idx_j, packed, rep, n_edges);
        dim3 g1(NBINS_PAD / 256, NPART);
        reduce1_kernel<<<g1, 256, 0, stream>>>(rep, partial);
        reduce2_kernel<<<(out_size + 255) / 256, 256, 0, stream>>>(
            partial, out, out_size);
    } else {
        // Fallback: direct-atomic path (R1)
        zero_kernel<<<(out_size + 255) / 256, 256, 0, stream>>>(out, out_size);
        const int nchunk = n_edges / 4;
        const int blocks = (nchunk + 255) / 256;
        if (ws_size >= packed_bytes) {
            unsigned int* packed = (unsigned int*)d_ws;
            pack_kernel<<<(n_atoms + 255) / 256, 256, 0, stream>>>(
                atomz, subsys, packed, n_atoms);
            zbl_atomic_kernel<true><<<blocks, 256, 0, stream>>>(
                d_ij, radii, idx_i, idx_j, packed, atomz, subsys, out, nchunk);
        } else {
            zbl_atomic_kernel<false><<<blocks, 256, 0, stream>>>(
                d_ij, radii, idx_i, idx_j, nullptr, atomz, subsys, out, nchunk);
        }
    }
}